// Round 1
// baseline (1131.687 us; speedup 1.0000x reference)
//
#include <hip/hip_runtime.h>
#include <hip/hip_bf16.h>

#define NN 100000
#define EE 1600000

using frag8 = __attribute__((ext_vector_type(8))) short;
using f32x4 = __attribute__((ext_vector_type(4))) float;

__device__ inline unsigned short f2bf(float f) {
    unsigned u = __float_as_uint(f);
    u = u + 0x7FFFu + ((u >> 16) & 1u);   // RNE
    return (unsigned short)(u >> 16);
}

// ---------------- CSR build ----------------

__global__ void hist_k(const int* __restrict__ d1, const int* __restrict__ d2,
                       int* __restrict__ c1, int* __restrict__ c2) {
    int e = blockIdx.x * 256 + threadIdx.x;
    if (e < EE) {
        atomicAdd(&c1[d1[e]], 1);
        atomicAdd(&c2[d2[e]], 1);
    }
}

// block-level exclusive scan over 1024 elems/block (256 thr x 4)
__global__ void scan_blocks_k(int* d1, int* d2, int* bs1, int* bs2, int n) {
    int* d  = blockIdx.y ? d2  : d1;
    int* bs = blockIdx.y ? bs2 : bs1;
    __shared__ int s[256];
    int t = threadIdx.x;
    int base = blockIdx.x * 1024 + t * 4;
    int v0 = (base + 0 < n) ? d[base + 0] : 0;
    int v1 = (base + 1 < n) ? d[base + 1] : 0;
    int v2 = (base + 2 < n) ? d[base + 2] : 0;
    int v3 = (base + 3 < n) ? d[base + 3] : 0;
    int tsum = v0 + v1 + v2 + v3;
    s[t] = tsum;
    __syncthreads();
    for (int off = 1; off < 256; off <<= 1) {
        int u = (t >= off) ? s[t - off] : 0;
        __syncthreads();
        s[t] += u;
        __syncthreads();
    }
    int ex = s[t] - tsum;
    if (base + 0 < n) d[base + 0] = ex;
    if (base + 1 < n) d[base + 1] = ex + v0;
    if (base + 2 < n) d[base + 2] = ex + v0 + v1;
    if (base + 3 < n) d[base + 3] = ex + v0 + v1 + v2;
    if (t == 255) bs[blockIdx.x] = s[255];
}

__global__ void scan_totals_k(int* bs1, int* bs2, int nb) {
    int* b = blockIdx.x ? bs2 : bs1;
    __shared__ int s[128];
    int t = threadIdx.x;
    int v = (t < nb) ? b[t] : 0;
    s[t] = v;
    __syncthreads();
    for (int off = 1; off < 128; off <<= 1) {
        int u = (t >= off) ? s[t - off] : 0;
        __syncthreads();
        s[t] += u;
        __syncthreads();
    }
    if (t < nb) b[t] = s[t] - v;   // exclusive
}

__global__ void scan_add_k(int* d1, int* d2, const int* bs1, const int* bs2, int n) {
    int* d = blockIdx.y ? d2 : d1;
    const int* bs = blockIdx.y ? bs2 : bs1;
    int add = bs[blockIdx.x];
    int base = blockIdx.x * 1024 + threadIdx.x * 4;
    #pragma unroll
    for (int i = 0; i < 4; i++)
        if (base + i < n) d[base + i] += add;
}

__global__ void scatter_k(const int* __restrict__ s1, const int* __restrict__ d1,
                          const int* __restrict__ s2, const int* __restrict__ d2,
                          const int* __restrict__ rs1, const int* __restrict__ rs2,
                          int* __restrict__ cur1, int* __restrict__ cur2,
                          int* __restrict__ c1, int* __restrict__ c2) {
    int e = blockIdx.x * 256 + threadIdx.x;
    if (e < EE) {
        int d = d1[e];
        int p = rs1[d] + atomicAdd(&cur1[d], 1);
        c1[p] = s1[e];
        d = d2[e];
        p = rs2[d] + atomicAdd(&cur2[d], 1);
        c2[p] = s2[e];
    }
}

// ---------------- W_embed fp32 -> bf16, transposed [64 cols][512 k], chunk-swizzled ----------------
// chunk = 8 bf16 (16B). swizzle within each 16-chunk (128-k) tile: phys = (ch&~15) | ((ch&15)^(col&7))

__global__ void wconv_k(const float* __restrict__ W, unsigned short* __restrict__ Wbf) {
    int id = blockIdx.x * 256 + threadIdx.x;
    if (id < 512 * 64) {
        int k = id >> 6, col = id & 63;   // W row-major [512][64]
        int ch = k >> 3, el = k & 7;
        int cs = (ch & ~15) | ((ch & 15) ^ (col & 7));
        Wbf[col * 512 + cs * 8 + el] = f2bf(W[id]);
    }
}

// ---------------- embed: h0 = relu(x @ W + b), bf16 MFMA ----------------
// block = 256 thr (4 waves), BM=64 rows, 64 cols, K=512 in 4 tiles of 128

__global__ __launch_bounds__(256) void embed_k(const float* __restrict__ x,
                                               const unsigned short* __restrict__ Wbf,
                                               const float* __restrict__ bias,
                                               float* __restrict__ h0) {
    __shared__ unsigned short sA[64 * 128];  // 16KB bf16, [row][128k] chunk-swizzled
    __shared__ unsigned short sW[64 * 128];  // 16KB bf16, [col][128k] chunk-swizzled
    int tid = threadIdx.x;
    int lane = tid & 63, wave = tid >> 6;
    int row0 = blockIdx.x * 64;
    f32x4 acc[4];
    #pragma unroll
    for (int n = 0; n < 4; n++) acc[n] = (f32x4){0.f, 0.f, 0.f, 0.f};

    int ccol = tid & 15;    // chunk within row (0..15)
    int rbase = tid >> 4;   // 0..15

    for (int kt = 0; kt < 4; ++kt) {
        // stage A: 64 rows x 128 k fp32 -> bf16 swizzled
        #pragma unroll
        for (int rr = 0; rr < 4; ++rr) {
            int r = rbase + rr * 16;
            int grow = row0 + r;
            float v[8];
            if (grow < NN) {
                const float4* px = (const float4*)(x + (size_t)grow * 512 + kt * 128 + ccol * 8);
                float4 p0 = px[0], p1 = px[1];
                v[0] = p0.x; v[1] = p0.y; v[2] = p0.z; v[3] = p0.w;
                v[4] = p1.x; v[5] = p1.y; v[6] = p1.z; v[7] = p1.w;
            } else {
                #pragma unroll
                for (int i = 0; i < 8; i++) v[i] = 0.f;
            }
            unsigned uu[4];
            #pragma unroll
            for (int i = 0; i < 4; i++)
                uu[i] = (unsigned)f2bf(v[2 * i]) | ((unsigned)f2bf(v[2 * i + 1]) << 16);
            int cs = ccol ^ (r & 7);
            uint4 pk; pk.x = uu[0]; pk.y = uu[1]; pk.z = uu[2]; pk.w = uu[3];
            *(uint4*)&sA[(r * 16 + cs) * 8] = pk;
        }
        // stage W tile (straight 16B-chunk copy; ws layout already swizzled)
        for (int q = tid; q < 1024; q += 256) {
            int col = q >> 4, c = q & 15;
            ((uint4*)sW)[q] = ((const uint4*)Wbf)[col * 64 + kt * 16 + c];
        }
        __syncthreads();
        #pragma unroll
        for (int kk = 0; kk < 4; ++kk) {
            int ar = wave * 16 + (lane & 15);
            int ac = (kk * 4 + (lane >> 4)) ^ (ar & 7);
            frag8 a = *(const frag8*)&sA[(ar * 16 + ac) * 8];
            #pragma unroll
            for (int n = 0; n < 4; n++) {
                int col = n * 16 + (lane & 15);
                int bc = (kk * 4 + (lane >> 4)) ^ (col & 7);
                frag8 b = *(const frag8*)&sW[(col * 16 + bc) * 8];
                acc[n] = __builtin_amdgcn_mfma_f32_16x16x32_bf16(a, b, acc[n], 0, 0, 0);
            }
        }
        __syncthreads();
    }
    // C/D layout: col = lane&15, row = (lane>>4)*4 + reg
    #pragma unroll
    for (int n = 0; n < 4; n++) {
        int col = n * 16 + (lane & 15);
        float bv = bias[col];
        #pragma unroll
        for (int i = 0; i < 4; i++) {
            int r = row0 + wave * 16 + (lane >> 4) * 4 + i;
            if (r < NN) {
                float vv = acc[n][i] + bv;
                h0[(size_t)r * 64 + col] = vv > 0.f ? vv : 0.f;
            }
        }
    }
}

// ---------------- logits init: logits = b_cls + h0 @ W_cls[0:64] ----------------

__global__ __launch_bounds__(256) void logits_init_k(const float* __restrict__ h0,
                                                     const float* __restrict__ Wc,
                                                     const float* __restrict__ bc,
                                                     float* __restrict__ logits) {
    int wave = threadIdx.x >> 6, lane = threadIdx.x & 63;
    int row = blockIdx.x * 4 + wave;
    if (lane < 40) {
        float acc = bc[lane];
        const float* hr = h0 + (size_t)row * 64;
        #pragma unroll 8
        for (int f = 0; f < 64; ++f) acc += hr[f] * Wc[f * 40 + lane];
        logits[(size_t)row * 40 + lane] = acc;
    }
}

// ---------------- pull-mode SpMM, fused classifier slice ----------------
// one wave per dst row; lane = feature (F=64) or feature pair (F=128)

template <int F>
__global__ __launch_bounds__(256) void spmm_fused_k(const float* __restrict__ h_in,
                                                    const int* __restrict__ row_start,
                                                    const int* __restrict__ csr_src,
                                                    float* __restrict__ h_out, int h_out_col,
                                                    const float* __restrict__ Wpart,
                                                    float* __restrict__ logits) {
    __shared__ float sh[4][F];
    int wave = threadIdx.x >> 6, lane = threadIdx.x & 63;
    int row = blockIdx.x * 4 + wave;
    int s = row_start[row], e = row_start[row + 1];

    if (F == 64) {
        float acc = 0.f;
        for (int t0 = s; t0 < e; t0 += 64) {
            int idxv = 0;
            if (t0 + lane < e) idxv = csr_src[t0 + lane];
            int cnt = e - t0; if (cnt > 64) cnt = 64;
            for (int j = 0; j < cnt; ++j) {
                int src = __shfl(idxv, j);
                acc += h_in[(size_t)src * 64 + lane];
            }
        }
        if (h_out) h_out[(size_t)row * 128 + h_out_col + lane] = acc;
        sh[wave][lane] = acc;
    } else {
        float ax = 0.f, ay = 0.f;
        const float2* hp = (const float2*)h_in;
        for (int t0 = s; t0 < e; t0 += 64) {
            int idxv = 0;
            if (t0 + lane < e) idxv = csr_src[t0 + lane];
            int cnt = e - t0; if (cnt > 64) cnt = 64;
            for (int j = 0; j < cnt; ++j) {
                int src = __shfl(idxv, j);
                float2 v = hp[(size_t)src * 64 + lane];
                ax += v.x; ay += v.y;
            }
        }
        sh[wave][2 * lane] = ax;
        sh[wave][2 * lane + 1] = ay;
    }
    __syncthreads();
    if (lane < 40) {
        float lacc = 0.f;
        #pragma unroll 8
        for (int f = 0; f < F; ++f) lacc += sh[wave][f] * Wpart[f * 40 + lane];
        logits[(size_t)row * 40 + lane] += lacc;
    }
}

// ---------------- log_softmax in place ----------------

__global__ __launch_bounds__(256) void lsm_k(float* __restrict__ logits) {
    int wave = threadIdx.x >> 6, lane = threadIdx.x & 63;
    int row = blockIdx.x * 4 + wave;
    float v = (lane < 40) ? logits[(size_t)row * 40 + lane] : -1e30f;
    float m = v;
    #pragma unroll
    for (int off = 32; off; off >>= 1) m = fmaxf(m, __shfl_xor(m, off));
    float ex = (lane < 40) ? __expf(v - m) : 0.f;
    float ssum = ex;
    #pragma unroll
    for (int off = 32; off; off >>= 1) ssum += __shfl_xor(ssum, off);
    float ls = __logf(ssum);
    if (lane < 40) logits[(size_t)row * 40 + lane] = v - m - ls;
}

// ---------------- launch ----------------

extern "C" void kernel_launch(void* const* d_in, const int* in_sizes, int n_in,
                              void* d_out, int out_size, void* d_ws, size_t ws_size,
                              hipStream_t stream) {
    const float* x       = (const float*)d_in[0];
    const float* W_embed = (const float*)d_in[1];
    const float* b_embed = (const float*)d_in[2];
    const float* W_cls   = (const float*)d_in[3];
    const float* b_cls   = (const float*)d_in[4];
    const int* a1src = (const int*)d_in[5];
    const int* a1dst = (const int*)d_in[6];
    const int* a2src = (const int*)d_in[7];
    const int* a2dst = (const int*)d_in[8];

    float* logits = (float*)d_out;
    float* ws = (float*)d_ws;

    // ws layout (units: 4B elements)
    const size_t OFF_H0   = 0;          // N*64 floats
    const size_t OFF_H1   = 6400000;    // N*128 floats
    const size_t OFF_RS1  = 19200000;   // N+1 ints
    const size_t OFF_RS2  = 19300004;   // N+1 ints
    const size_t OFF_CUR1 = 19400008;   // N ints
    const size_t OFF_CUR2 = 19500008;   // N ints
    const size_t OFF_BS1  = 19600008;   // 128 ints
    const size_t OFF_BS2  = 19600136;   // 128 ints
    const size_t OFF_CSR1 = 19600264;   // E ints
    const size_t OFF_CSR2 = 21200264;   // E ints
    const size_t OFF_WBF  = 22800264;   // 32768 ushorts (16384 slots), 16B-aligned

    float* h0 = ws + OFF_H0;
    float* h1 = ws + OFF_H1;
    int* rs1  = (int*)(ws + OFF_RS1);
    int* rs2  = (int*)(ws + OFF_RS2);
    int* cur1 = (int*)(ws + OFF_CUR1);
    int* cur2 = (int*)(ws + OFF_CUR2);
    int* bs1  = (int*)(ws + OFF_BS1);
    int* bs2  = (int*)(ws + OFF_BS2);
    int* csr1 = (int*)(ws + OFF_CSR1);
    int* csr2 = (int*)(ws + OFF_CSR2);
    unsigned short* wbf = (unsigned short*)(ws + OFF_WBF);

    // zero counts/cursors/block-sums in one memset
    hipMemsetAsync(ws + OFF_RS1, 0, (OFF_CSR1 - OFF_RS1) * 4, stream);

    const int NB = 98;  // ceil((N+1)/1024)

    hist_k<<<EE / 256, 256, 0, stream>>>(a1dst, a2dst, rs1, rs2);
    scan_blocks_k<<<dim3(NB, 2), 256, 0, stream>>>(rs1, rs2, bs1, bs2, NN + 1);
    scan_totals_k<<<2, 128, 0, stream>>>(bs1, bs2, NB);
    scan_add_k<<<dim3(NB, 2), 256, 0, stream>>>(rs1, rs2, bs1, bs2, NN + 1);
    scatter_k<<<EE / 256, 256, 0, stream>>>(a1src, a1dst, a2src, a2dst,
                                            rs1, rs2, cur1, cur2, csr1, csr2);

    wconv_k<<<128, 256, 0, stream>>>(W_embed, wbf);
    embed_k<<<(NN + 63) / 64, 256, 0, stream>>>(x, wbf, b_embed, h0);
    logits_init_k<<<NN / 4, 256, 0, stream>>>(h0, W_cls, b_cls, logits);

    spmm_fused_k<64><<<NN / 4, 256, 0, stream>>>(h0, rs1, csr1, h1, 0,  W_cls + 64 * 40,  logits);
    spmm_fused_k<64><<<NN / 4, 256, 0, stream>>>(h0, rs2, csr2, h1, 64, W_cls + 128 * 40, logits);
    spmm_fused_k<128><<<NN / 4, 256, 0, stream>>>(h1, rs1, csr1, nullptr, 0, W_cls + 192 * 40, logits);
    spmm_fused_k<128><<<NN / 4, 256, 0, stream>>>(h1, rs2, csr2, nullptr, 0, W_cls + 320 * 40, logits);

    lsm_k<<<NN / 4, 256, 0, stream>>>(logits);
}

// Round 2
// 790.237 us; speedup vs baseline: 1.4321x; 1.4321x over previous
//
#include <hip/hip_runtime.h>
#include <hip/hip_bf16.h>

#define NN 100000
#define EE 1600000

using frag8 = __attribute__((ext_vector_type(8))) short;
using f32x4 = __attribute__((ext_vector_type(4))) float;

__device__ inline unsigned short f2bf(float f) {
    unsigned u = __float_as_uint(f);
    u = u + 0x7FFFu + ((u >> 16) & 1u);   // RNE
    return (unsigned short)(u >> 16);
}
__device__ inline float bf2f(unsigned short u) {
    return __uint_as_float(((unsigned)u) << 16);
}

// ---------------- CSR build ----------------

__global__ void hist_k(const int* __restrict__ d1, const int* __restrict__ d2,
                       int* __restrict__ c1, int* __restrict__ c2) {
    int e = blockIdx.x * 256 + threadIdx.x;
    if (e < EE) {
        atomicAdd(&c1[d1[e]], 1);
        atomicAdd(&c2[d2[e]], 1);
    }
}

__global__ void scan_blocks_k(int* d1, int* d2, int* bs1, int* bs2, int n) {
    int* d  = blockIdx.y ? d2  : d1;
    int* bs = blockIdx.y ? bs2 : bs1;
    __shared__ int s[256];
    int t = threadIdx.x;
    int base = blockIdx.x * 1024 + t * 4;
    int v0 = (base + 0 < n) ? d[base + 0] : 0;
    int v1 = (base + 1 < n) ? d[base + 1] : 0;
    int v2 = (base + 2 < n) ? d[base + 2] : 0;
    int v3 = (base + 3 < n) ? d[base + 3] : 0;
    int tsum = v0 + v1 + v2 + v3;
    s[t] = tsum;
    __syncthreads();
    for (int off = 1; off < 256; off <<= 1) {
        int u = (t >= off) ? s[t - off] : 0;
        __syncthreads();
        s[t] += u;
        __syncthreads();
    }
    int ex = s[t] - tsum;
    if (base + 0 < n) d[base + 0] = ex;
    if (base + 1 < n) d[base + 1] = ex + v0;
    if (base + 2 < n) d[base + 2] = ex + v0 + v1;
    if (base + 3 < n) d[base + 3] = ex + v0 + v1 + v2;
    if (t == 255) bs[blockIdx.x] = s[255];
}

__global__ void scan_totals_k(int* bs1, int* bs2, int nb) {
    int* b = blockIdx.x ? bs2 : bs1;
    __shared__ int s[128];
    int t = threadIdx.x;
    int v = (t < nb) ? b[t] : 0;
    s[t] = v;
    __syncthreads();
    for (int off = 1; off < 128; off <<= 1) {
        int u = (t >= off) ? s[t - off] : 0;
        __syncthreads();
        s[t] += u;
        __syncthreads();
    }
    if (t < nb) b[t] = s[t] - v;   // exclusive
}

__global__ void scan_add_k(int* d1, int* d2, const int* bs1, const int* bs2, int n) {
    int* d = blockIdx.y ? d2 : d1;
    const int* bs = blockIdx.y ? bs2 : bs1;
    int add = bs[blockIdx.x];
    int base = blockIdx.x * 1024 + threadIdx.x * 4;
    #pragma unroll
    for (int i = 0; i < 4; i++)
        if (base + i < n) d[base + i] += add;
}

__global__ void scatter_k(const int* __restrict__ s1, const int* __restrict__ d1,
                          const int* __restrict__ s2, const int* __restrict__ d2,
                          const int* __restrict__ rs1, const int* __restrict__ rs2,
                          int* __restrict__ cur1, int* __restrict__ cur2,
                          int* __restrict__ c1, int* __restrict__ c2) {
    int e = blockIdx.x * 256 + threadIdx.x;
    if (e < EE) {
        int d = d1[e];
        int p = rs1[d] + atomicAdd(&cur1[d], 1);
        c1[p] = s1[e];
        d = d2[e];
        p = rs2[d] + atomicAdd(&cur2[d], 1);
        c2[p] = s2[e];
    }
}

// ---------------- W_embed fp32 -> bf16, transposed + chunk-swizzled ----------------

__global__ void wconv_k(const float* __restrict__ W, unsigned short* __restrict__ Wbf) {
    int id = blockIdx.x * 256 + threadIdx.x;
    if (id < 512 * 64) {
        int k = id >> 6, col = id & 63;   // W row-major [512][64]
        int ch = k >> 3, el = k & 7;
        int cs = (ch & ~15) | ((ch & 15) ^ (col & 7));
        Wbf[col * 512 + cs * 8 + el] = f2bf(W[id]);
    }
}

// ---------------- embed: h0 = relu(x @ W + b), bf16 MFMA, bf16 output ----------------

__global__ __launch_bounds__(256) void embed_k(const float* __restrict__ x,
                                               const unsigned short* __restrict__ Wbf,
                                               const float* __restrict__ bias,
                                               unsigned short* __restrict__ h0) {
    __shared__ unsigned short sA[64 * 128];
    __shared__ unsigned short sW[64 * 128];
    int tid = threadIdx.x;
    int lane = tid & 63, wave = tid >> 6;
    int row0 = blockIdx.x * 64;
    f32x4 acc[4];
    #pragma unroll
    for (int n = 0; n < 4; n++) acc[n] = (f32x4){0.f, 0.f, 0.f, 0.f};

    int ccol = tid & 15;
    int rbase = tid >> 4;

    for (int kt = 0; kt < 4; ++kt) {
        #pragma unroll
        for (int rr = 0; rr < 4; ++rr) {
            int r = rbase + rr * 16;
            int grow = row0 + r;
            float v[8];
            if (grow < NN) {
                const float4* px = (const float4*)(x + (size_t)grow * 512 + kt * 128 + ccol * 8);
                float4 p0 = px[0], p1 = px[1];
                v[0] = p0.x; v[1] = p0.y; v[2] = p0.z; v[3] = p0.w;
                v[4] = p1.x; v[5] = p1.y; v[6] = p1.z; v[7] = p1.w;
            } else {
                #pragma unroll
                for (int i = 0; i < 8; i++) v[i] = 0.f;
            }
            unsigned uu[4];
            #pragma unroll
            for (int i = 0; i < 4; i++)
                uu[i] = (unsigned)f2bf(v[2 * i]) | ((unsigned)f2bf(v[2 * i + 1]) << 16);
            int cs = ccol ^ (r & 7);
            uint4 pk; pk.x = uu[0]; pk.y = uu[1]; pk.z = uu[2]; pk.w = uu[3];
            *(uint4*)&sA[(r * 16 + cs) * 8] = pk;
        }
        for (int q = tid; q < 1024; q += 256) {
            int col = q >> 4, c = q & 15;
            ((uint4*)sW)[q] = ((const uint4*)Wbf)[col * 64 + kt * 16 + c];
        }
        __syncthreads();
        #pragma unroll
        for (int kk = 0; kk < 4; ++kk) {
            int ar = wave * 16 + (lane & 15);
            int ac = (kk * 4 + (lane >> 4)) ^ (ar & 7);
            frag8 a = *(const frag8*)&sA[(ar * 16 + ac) * 8];
            #pragma unroll
            for (int n = 0; n < 4; n++) {
                int col = n * 16 + (lane & 15);
                int bc = (kk * 4 + (lane >> 4)) ^ (col & 7);
                frag8 b = *(const frag8*)&sW[(col * 16 + bc) * 8];
                acc[n] = __builtin_amdgcn_mfma_f32_16x16x32_bf16(a, b, acc[n], 0, 0, 0);
            }
        }
        __syncthreads();
    }
    #pragma unroll
    for (int n = 0; n < 4; n++) {
        int col = n * 16 + (lane & 15);
        float bv = bias[col];
        #pragma unroll
        for (int i = 0; i < 4; i++) {
            int r = row0 + wave * 16 + (lane >> 4) * 4 + i;
            if (r < NN) {
                float vv = acc[n][i] + bv;
                h0[(size_t)r * 64 + col] = f2bf(vv > 0.f ? vv : 0.f);
            }
        }
    }
}

// ---------------- gathers (pull-mode, 4x unrolled) ----------------

__device__ inline float gather64(const unsigned short* __restrict__ h,
                                 const int* __restrict__ csr, int s, int e, int lane) {
    float acc = 0.f;
    for (int t0 = s; t0 < e; t0 += 64) {
        int rem = e - t0;
        int idxv = 0;
        if (lane < rem) idxv = csr[t0 + lane];
        int cnt = rem < 64 ? rem : 64;
        int j = 0;
        for (; j + 4 <= cnt; j += 4) {
            int s0 = __shfl(idxv, j),     s1 = __shfl(idxv, j + 1);
            int s2 = __shfl(idxv, j + 2), s3 = __shfl(idxv, j + 3);
            float v0 = bf2f(h[(size_t)s0 * 64 + lane]);
            float v1 = bf2f(h[(size_t)s1 * 64 + lane]);
            float v2 = bf2f(h[(size_t)s2 * 64 + lane]);
            float v3 = bf2f(h[(size_t)s3 * 64 + lane]);
            acc += (v0 + v1) + (v2 + v3);
        }
        for (; j < cnt; ++j) {
            int s0 = __shfl(idxv, j);
            acc += bf2f(h[(size_t)s0 * 64 + lane]);
        }
    }
    return acc;
}

__device__ inline void gather128(const unsigned* __restrict__ h,
                                 const int* __restrict__ csr, int s, int e, int lane,
                                 float& ax, float& ay) {
    float a = 0.f, b = 0.f;
    for (int t0 = s; t0 < e; t0 += 64) {
        int rem = e - t0;
        int idxv = 0;
        if (lane < rem) idxv = csr[t0 + lane];
        int cnt = rem < 64 ? rem : 64;
        int j = 0;
        for (; j + 4 <= cnt; j += 4) {
            int s0 = __shfl(idxv, j),     s1 = __shfl(idxv, j + 1);
            int s2 = __shfl(idxv, j + 2), s3 = __shfl(idxv, j + 3);
            unsigned u0 = h[(size_t)s0 * 64 + lane];
            unsigned u1 = h[(size_t)s1 * 64 + lane];
            unsigned u2 = h[(size_t)s2 * 64 + lane];
            unsigned u3 = h[(size_t)s3 * 64 + lane];
            a += (__uint_as_float(u0 << 16) + __uint_as_float(u1 << 16)) +
                 (__uint_as_float(u2 << 16) + __uint_as_float(u3 << 16));
            b += (__uint_as_float(u0 & 0xffff0000u) + __uint_as_float(u1 & 0xffff0000u)) +
                 (__uint_as_float(u2 & 0xffff0000u) + __uint_as_float(u3 & 0xffff0000u));
        }
        for (; j < cnt; ++j) {
            int s0 = __shfl(idxv, j);
            unsigned u0 = h[(size_t)s0 * 64 + lane];
            a += __uint_as_float(u0 << 16);
            b += __uint_as_float(u0 & 0xffff0000u);
        }
    }
    ax = a; ay = b;
}

// ---------------- round 1: r1,r2 = spmm(h0); h1=[r1|r2]; logits = b + [h0|r1|r2]·W[0:192] ----------------

__global__ __launch_bounds__(256) void round1_k(const unsigned short* __restrict__ h0,
                                                const int* __restrict__ rs1,
                                                const int* __restrict__ csr1,
                                                const int* __restrict__ rs2,
                                                const int* __restrict__ csr2,
                                                unsigned short* __restrict__ h1,
                                                const float* __restrict__ Wc,
                                                const float* __restrict__ bc,
                                                float* __restrict__ logits) {
    __shared__ float sh[4][192];
    int wave = threadIdx.x >> 6, lane = threadIdx.x & 63;
    int row = blockIdx.x * 4 + wave;

    sh[wave][lane] = bf2f(h0[(size_t)row * 64 + lane]);

    int s1 = rs1[row], e1 = rs1[row + 1];
    int s2 = rs2[row], e2 = rs2[row + 1];
    float a1 = gather64(h0, csr1, s1, e1, lane);
    float a2 = gather64(h0, csr2, s2, e2, lane);

    h1[(size_t)row * 128 + lane]      = f2bf(a1);
    h1[(size_t)row * 128 + 64 + lane] = f2bf(a2);
    sh[wave][64 + lane]  = a1;
    sh[wave][128 + lane] = a2;

    // per-wave LDS only: no __syncthreads needed
    if (lane < 40) {
        float lacc = bc[lane];
        #pragma unroll 8
        for (int f = 0; f < 192; ++f) lacc += sh[wave][f] * Wc[f * 40 + lane];
        logits[(size_t)row * 40 + lane] = lacc;
    }
}

// ---------------- round 2: r3,r4 = spmm(h1); logits += [r3|r4]·W[192:448]; log_softmax ----------------

__global__ __launch_bounds__(256) void round2_k(const unsigned* __restrict__ h1,
                                                const int* __restrict__ rs1,
                                                const int* __restrict__ csr1,
                                                const int* __restrict__ rs2,
                                                const int* __restrict__ csr2,
                                                const float* __restrict__ Wc,
                                                float* __restrict__ logits) {
    __shared__ float sh[4][256];
    int wave = threadIdx.x >> 6, lane = threadIdx.x & 63;
    int row = blockIdx.x * 4 + wave;

    int s1 = rs1[row], e1 = rs1[row + 1];
    int s2 = rs2[row], e2 = rs2[row + 1];
    float ax1, ay1, ax2, ay2;
    gather128(h1, csr1, s1, e1, lane, ax1, ay1);
    gather128(h1, csr2, s2, e2, lane, ax2, ay2);

    float2* shp = (float2*)sh[wave];
    shp[lane]      = make_float2(ax1, ay1);   // r3 features 2*lane, 2*lane+1
    shp[64 + lane] = make_float2(ax2, ay2);   // r4

    float v = -1e30f;
    if (lane < 40) {
        float lacc = logits[(size_t)row * 40 + lane];
        #pragma unroll 8
        for (int f = 0; f < 256; ++f) lacc += sh[wave][f] * Wc[f * 40 + lane];
        v = lacc;
    }
    float m = v;
    #pragma unroll
    for (int off = 32; off; off >>= 1) m = fmaxf(m, __shfl_xor(m, off));
    float ex = (lane < 40) ? __expf(v - m) : 0.f;
    float ssum = ex;
    #pragma unroll
    for (int off = 32; off; off >>= 1) ssum += __shfl_xor(ssum, off);
    float ls = __logf(ssum);
    if (lane < 40) logits[(size_t)row * 40 + lane] = v - m - ls;
}

// ---------------- launch ----------------

extern "C" void kernel_launch(void* const* d_in, const int* in_sizes, int n_in,
                              void* d_out, int out_size, void* d_ws, size_t ws_size,
                              hipStream_t stream) {
    const float* x       = (const float*)d_in[0];
    const float* W_embed = (const float*)d_in[1];
    const float* b_embed = (const float*)d_in[2];
    const float* W_cls   = (const float*)d_in[3];
    const float* b_cls   = (const float*)d_in[4];
    const int* a1src = (const int*)d_in[5];
    const int* a1dst = (const int*)d_in[6];
    const int* a2src = (const int*)d_in[7];
    const int* a2dst = (const int*)d_in[8];

    float* logits = (float*)d_out;
    float* ws = (float*)d_ws;

    // ws layout (units: 4B elements)
    const size_t OFF_H0   = 0;          // N*64 ushorts = 3.2M floats
    const size_t OFF_H1   = 3200000;    // N*128 ushorts = 6.4M floats
    const size_t OFF_RS1  = 9600000;    // N+1 ints
    const size_t OFF_RS2  = 9700004;
    const size_t OFF_CUR1 = 9800008;    // N ints
    const size_t OFF_CUR2 = 9900008;
    const size_t OFF_BS1  = 10000008;   // 128 ints
    const size_t OFF_BS2  = 10000136;
    const size_t OFF_CSR1 = 10000264;   // E ints
    const size_t OFF_CSR2 = 11600264;
    const size_t OFF_WBF  = 13200264;   // 32768 ushorts (16B-aligned)

    unsigned short* h0 = (unsigned short*)(ws + OFF_H0);
    unsigned short* h1 = (unsigned short*)(ws + OFF_H1);
    int* rs1  = (int*)(ws + OFF_RS1);
    int* rs2  = (int*)(ws + OFF_RS2);
    int* cur1 = (int*)(ws + OFF_CUR1);
    int* cur2 = (int*)(ws + OFF_CUR2);
    int* bs1  = (int*)(ws + OFF_BS1);
    int* bs2  = (int*)(ws + OFF_BS2);
    int* csr1 = (int*)(ws + OFF_CSR1);
    int* csr2 = (int*)(ws + OFF_CSR2);
    unsigned short* wbf = (unsigned short*)(ws + OFF_WBF);

    hipMemsetAsync(ws + OFF_RS1, 0, (OFF_CSR1 - OFF_RS1) * 4, stream);

    const int NB = 98;  // ceil((N+1)/1024)

    hist_k<<<EE / 256, 256, 0, stream>>>(a1dst, a2dst, rs1, rs2);
    scan_blocks_k<<<dim3(NB, 2), 256, 0, stream>>>(rs1, rs2, bs1, bs2, NN + 1);
    scan_totals_k<<<2, 128, 0, stream>>>(bs1, bs2, NB);
    scan_add_k<<<dim3(NB, 2), 256, 0, stream>>>(rs1, rs2, bs1, bs2, NN + 1);
    scatter_k<<<EE / 256, 256, 0, stream>>>(a1src, a1dst, a2src, a2dst,
                                            rs1, rs2, cur1, cur2, csr1, csr2);

    wconv_k<<<128, 256, 0, stream>>>(W_embed, wbf);
    embed_k<<<(NN + 63) / 64, 256, 0, stream>>>(x, wbf, b_embed, h0);

    round1_k<<<NN / 4, 256, 0, stream>>>(h0, rs1, csr1, rs2, csr2, h1,
                                         W_cls, b_cls, logits);
    round2_k<<<NN / 4, 256, 0, stream>>>((const unsigned*)h1, rs1, csr1, rs2, csr2,
                                         W_cls + 192 * 40, logits);
}

// Round 4
// 566.091 us; speedup vs baseline: 1.9991x; 1.3960x over previous
//
#include <hip/hip_runtime.h>
#include <hip/hip_bf16.h>

#define NN 100000
#define EE 1600000

using frag8 = __attribute__((ext_vector_type(8))) short;
using f32x4 = __attribute__((ext_vector_type(4))) float;

__device__ inline unsigned short f2bf(float f) {
    unsigned u = __float_as_uint(f);
    u = u + 0x7FFFu + ((u >> 16) & 1u);   // RNE
    return (unsigned short)(u >> 16);
}
__device__ inline float bf2f(unsigned short u) {
    return __uint_as_float(((unsigned)u) << 16);
}

// ---------------- CSR build ----------------

__global__ void hist_k(const int* __restrict__ d1, const int* __restrict__ d2,
                       int* __restrict__ c1, int* __restrict__ c2) {
    int e = blockIdx.x * 256 + threadIdx.x;
    if (e < EE) {
        atomicAdd(&c1[d1[e]], 1);
        atomicAdd(&c2[d2[e]], 1);
    }
}

__global__ void scan_blocks_k(int* d1, int* d2, int* bs1, int* bs2, int n) {
    int* d  = blockIdx.y ? d2  : d1;
    int* bs = blockIdx.y ? bs2 : bs1;
    __shared__ int s[256];
    int t = threadIdx.x;
    int base = blockIdx.x * 1024 + t * 4;
    int v0 = (base + 0 < n) ? d[base + 0] : 0;
    int v1 = (base + 1 < n) ? d[base + 1] : 0;
    int v2 = (base + 2 < n) ? d[base + 2] : 0;
    int v3 = (base + 3 < n) ? d[base + 3] : 0;
    int tsum = v0 + v1 + v2 + v3;
    s[t] = tsum;
    __syncthreads();
    for (int off = 1; off < 256; off <<= 1) {
        int u = (t >= off) ? s[t - off] : 0;
        __syncthreads();
        s[t] += u;
        __syncthreads();
    }
    int ex = s[t] - tsum;
    if (base + 0 < n) d[base + 0] = ex;
    if (base + 1 < n) d[base + 1] = ex + v0;
    if (base + 2 < n) d[base + 2] = ex + v0 + v1;
    if (base + 3 < n) d[base + 3] = ex + v0 + v1 + v2;
    if (t == 255) bs[blockIdx.x] = s[255];
}

__global__ void scan_totals_k(int* bs1, int* bs2, int nb) {
    int* b = blockIdx.x ? bs2 : bs1;
    __shared__ int s[128];
    int t = threadIdx.x;
    int v = (t < nb) ? b[t] : 0;
    s[t] = v;
    __syncthreads();
    for (int off = 1; off < 128; off <<= 1) {
        int u = (t >= off) ? s[t - off] : 0;
        __syncthreads();
        s[t] += u;
        __syncthreads();
    }
    if (t < nb) b[t] = s[t] - v;   // exclusive
}

__global__ void scan_add_k(int* d1, int* d2, const int* bs1, const int* bs2, int n) {
    int* d = blockIdx.y ? d2 : d1;
    const int* bs = blockIdx.y ? bs2 : bs1;
    int add = bs[blockIdx.x];
    int base = blockIdx.x * 1024 + threadIdx.x * 4;
    #pragma unroll
    for (int i = 0; i < 4; i++)
        if (base + i < n) d[base + i] += add;
}

__global__ void scatter_k(const int* __restrict__ s1, const int* __restrict__ d1,
                          const int* __restrict__ s2, const int* __restrict__ d2,
                          const int* __restrict__ rs1, const int* __restrict__ rs2,
                          int* __restrict__ cur1, int* __restrict__ cur2,
                          int* __restrict__ c1, int* __restrict__ c2) {
    int e = blockIdx.x * 256 + threadIdx.x;
    if (e < EE) {
        int d = d1[e];
        int p = rs1[d] + atomicAdd(&cur1[d], 1);
        c1[p] = s1[e];
        d = d2[e];
        p = rs2[d] + atomicAdd(&cur2[d], 1);
        c2[p] = s2[e];
    }
}

// ---------------- W_embed fp32 -> bf16, transposed + chunk-swizzled (16-chunk groups) ----------------

__global__ void wconv_k(const float* __restrict__ W, unsigned short* __restrict__ Wbf) {
    int id = blockIdx.x * 256 + threadIdx.x;
    if (id < 512 * 64) {
        int k = id >> 6, col = id & 63;   // W row-major [512][64]
        int ch = k >> 3, el = k & 7;
        int cs = (ch & ~15) | ((ch & 15) ^ (col & 7));
        Wbf[col * 512 + cs * 8 + el] = f2bf(W[id]);
    }
}

// ---------------- W_cls -> Wbig bf16 [128 cols][192 k], 8-chunk-group swizzle ----------------
// col<40: logits cols (Wc rows 0..191); 40..79: z1 = h1·Wc[192:320]; 80..119: z2 = h1·Wc[320:448]

__global__ void wcls_k(const float* __restrict__ Wc, unsigned short* __restrict__ Wbig) {
    int id = blockIdx.x * 256 + threadIdx.x;   // 192*128
    int k = id >> 7, col = id & 127;
    float v = 0.f;
    if (col < 40) v = Wc[k * 40 + col];
    else if (col < 80)  { if (k >= 64) v = Wc[(192 + k - 64) * 40 + (col - 40)]; }
    else if (col < 120) { if (k >= 64) v = Wc[(320 + k - 64) * 40 + (col - 80)]; }
    int ch = k >> 3, el = k & 7;
    int phys = (ch & ~7) | ((ch & 7) ^ (col & 7));
    Wbig[col * 192 + phys * 8 + el] = f2bf(v);
}

// ---------------- embed: hcat[:,0:64] = relu(x @ W + b), bf16 MFMA ----------------

__global__ __launch_bounds__(256) void embed_k(const float* __restrict__ x,
                                               const unsigned short* __restrict__ Wbf,
                                               const float* __restrict__ bias,
                                               unsigned short* __restrict__ hcat) {
    __shared__ unsigned short sA[64 * 128];
    __shared__ unsigned short sW[64 * 128];
    int tid = threadIdx.x;
    int lane = tid & 63, wave = tid >> 6;
    int row0 = blockIdx.x * 64;
    f32x4 acc[4];
    #pragma unroll
    for (int n = 0; n < 4; n++) acc[n] = (f32x4){0.f, 0.f, 0.f, 0.f};

    int ccol = tid & 15;
    int rbase = tid >> 4;

    for (int kt = 0; kt < 4; ++kt) {
        #pragma unroll
        for (int rr = 0; rr < 4; ++rr) {
            int r = rbase + rr * 16;
            int grow = row0 + r;
            float v[8];
            if (grow < NN) {
                const float4* px = (const float4*)(x + (size_t)grow * 512 + kt * 128 + ccol * 8);
                float4 p0 = px[0], p1 = px[1];
                v[0] = p0.x; v[1] = p0.y; v[2] = p0.z; v[3] = p0.w;
                v[4] = p1.x; v[5] = p1.y; v[6] = p1.z; v[7] = p1.w;
            } else {
                #pragma unroll
                for (int i = 0; i < 8; i++) v[i] = 0.f;
            }
            unsigned uu[4];
            #pragma unroll
            for (int i = 0; i < 4; i++)
                uu[i] = (unsigned)f2bf(v[2 * i]) | ((unsigned)f2bf(v[2 * i + 1]) << 16);
            int cs = ccol ^ (r & 7);
            uint4 pk; pk.x = uu[0]; pk.y = uu[1]; pk.z = uu[2]; pk.w = uu[3];
            *(uint4*)&sA[(r * 16 + cs) * 8] = pk;
        }
        for (int q = tid; q < 1024; q += 256) {
            int col = q >> 4, c = q & 15;
            ((uint4*)sW)[q] = ((const uint4*)Wbf)[col * 64 + kt * 16 + c];
        }
        __syncthreads();
        #pragma unroll
        for (int kk = 0; kk < 4; ++kk) {
            int ar = wave * 16 + (lane & 15);
            int ac = (kk * 4 + (lane >> 4)) ^ (ar & 7);
            frag8 a = *(const frag8*)&sA[(ar * 16 + ac) * 8];
            #pragma unroll
            for (int n = 0; n < 4; n++) {
                int col = n * 16 + (lane & 15);
                int bc = (kk * 4 + (lane >> 4)) ^ (col & 7);
                frag8 b = *(const frag8*)&sW[(col * 16 + bc) * 8];
                acc[n] = __builtin_amdgcn_mfma_f32_16x16x32_bf16(a, b, acc[n], 0, 0, 0);
            }
        }
        __syncthreads();
    }
    #pragma unroll
    for (int n = 0; n < 4; n++) {
        int col = n * 16 + (lane & 15);
        float bv = bias[col];
        #pragma unroll
        for (int i = 0; i < 4; i++) {
            int r = row0 + wave * 16 + (lane >> 4) * 4 + i;
            if (r < NN) {
                float vv = acc[n][i] + bv;
                hcat[(size_t)r * 192 + col] = f2bf(vv > 0.f ? vv : 0.f);
            }
        }
    }
}

// ---------------- round 1: hcat[:,64:192] = [A1·h0 | A2·h0]  (proven R2 gather shape) ----------------
// one wave per row; lane = feature 0..63; h0 = hcat cols 0..63 (row stride 192 ushorts)

__device__ inline float gatherH0(const unsigned short* h, const int* __restrict__ csr,
                                 int s, int e, int lane) {
    float acc = 0.f;
    for (int t0 = s; t0 < e; t0 += 64) {
        int rem = e - t0;
        int idxv = 0;
        if (lane < rem) idxv = csr[t0 + lane];
        int cnt = rem < 64 ? rem : 64;
        int j = 0;
        for (; j + 4 <= cnt; j += 4) {
            int s0 = __shfl(idxv, j),     s1 = __shfl(idxv, j + 1);
            int s2 = __shfl(idxv, j + 2), s3 = __shfl(idxv, j + 3);
            float v0 = bf2f(h[(size_t)s0 * 192 + lane]);
            float v1 = bf2f(h[(size_t)s1 * 192 + lane]);
            float v2 = bf2f(h[(size_t)s2 * 192 + lane]);
            float v3 = bf2f(h[(size_t)s3 * 192 + lane]);
            acc += (v0 + v1) + (v2 + v3);
        }
        for (; j < cnt; ++j) {
            int s0 = __shfl(idxv, j);
            acc += bf2f(h[(size_t)s0 * 192 + lane]);
        }
    }
    return acc;
}

__global__ __launch_bounds__(256) void round1_k(unsigned short* hc,
                                                const int* __restrict__ rs1,
                                                const int* __restrict__ csr1,
                                                const int* __restrict__ rs2,
                                                const int* __restrict__ csr2) {
    int wave = threadIdx.x >> 6, lane = threadIdx.x & 63;
    int row = blockIdx.x * 4 + wave;

    float a1 = gatherH0(hc, csr1, rs1[row], rs1[row + 1], lane);
    float a2 = gatherH0(hc, csr2, rs2[row], rs2[row + 1], lane);

    hc[(size_t)row * 192 + 64 + lane]  = f2bf(a1);
    hc[(size_t)row * 192 + 128 + lane] = f2bf(a2);
}

// ---------------- gemm: [logits | z1 | z2] = hcat(Nx192) @ Wbig(192x120) ----------------
// BM=64, 4 waves, each wave 16 rows x 128 cols; K in 3 tiles of 64

__global__ __launch_bounds__(256) void gemm_k(const unsigned short* __restrict__ hcat,
                                              const unsigned short* __restrict__ Wbig,
                                              const float* __restrict__ bc,
                                              float* __restrict__ logits,
                                              unsigned short* __restrict__ zcat) {
    __shared__ unsigned short sA[64 * 64];    // 8KB: [row][8 chunks], chunk swz c^(r&7)
    __shared__ unsigned short sB[128 * 64];   // 16KB: [col][8 chunks], pre-swizzled
    int tid = threadIdx.x;
    int lane = tid & 63, wave = tid >> 6;
    int row0 = blockIdx.x * 64;
    f32x4 acc[8];
    #pragma unroll
    for (int n = 0; n < 8; n++) acc[n] = (f32x4){0.f, 0.f, 0.f, 0.f};

    for (int kt = 0; kt < 3; ++kt) {
        #pragma unroll
        for (int q = tid; q < 512; q += 256) {
            int r = q >> 3, c = q & 7;
            int phys = c ^ (r & 7);
            ((uint4*)sA)[r * 8 + phys] = ((const uint4*)hcat)[(size_t)(row0 + r) * 24 + kt * 8 + c];
        }
        #pragma unroll
        for (int q = tid; q < 1024; q += 256) {
            int col = q >> 3, c = q & 7;
            ((uint4*)sB)[q] = ((const uint4*)Wbig)[col * 24 + kt * 8 + c];
        }
        __syncthreads();
        #pragma unroll
        for (int kk = 0; kk < 2; ++kk) {
            int ar = wave * 16 + (lane & 15);
            int ac = (kk * 4 + (lane >> 4)) ^ (ar & 7);
            frag8 a = *(const frag8*)&sA[(ar * 8 + ac) * 8];
            #pragma unroll
            for (int n = 0; n < 8; n++) {
                int col = n * 16 + (lane & 15);
                int bcc = (kk * 4 + (lane >> 4)) ^ (col & 7);
                frag8 b = *(const frag8*)&sB[(col * 8 + bcc) * 8];
                acc[n] = __builtin_amdgcn_mfma_f32_16x16x32_bf16(a, b, acc[n], 0, 0, 0);
            }
        }
        __syncthreads();
    }
    #pragma unroll
    for (int n = 0; n < 8; n++) {
        int col = n * 16 + (lane & 15);
        float bv = (col < 40) ? bc[col] : 0.f;
        #pragma unroll
        for (int i = 0; i < 4; i++) {
            int r = row0 + wave * 16 + (lane >> 4) * 4 + i;
            if (r < NN) {
                float vv = acc[n][i];
                if (col < 40) {
                    logits[(size_t)r * 40 + col] = vv + bv;
                } else if (col < 80) {
                    zcat[(size_t)r * 128 + (col - 40)] = f2bf(vv);
                } else if (col < 120) {
                    zcat[(size_t)r * 128 + 64 + (col - 80)] = f2bf(vv);
                }
            }
        }
    }
}

// ---------------- round 2: logits += A1·z1 + A2·z2; log_softmax (proven R2 shape) ----------------
// zcat rows: [z1(40) pad(24) z2(40) pad(24)] ushorts; lanes 40..63 load pad, never used

__device__ inline float gatherZ(const unsigned short* __restrict__ z, int zoff,
                                const int* __restrict__ csr, int s, int e, int lane) {
    float acc = 0.f;
    for (int t0 = s; t0 < e; t0 += 64) {
        int rem = e - t0;
        int idxv = 0;
        if (lane < rem) idxv = csr[t0 + lane];
        int cnt = rem < 64 ? rem : 64;
        int j = 0;
        for (; j + 4 <= cnt; j += 4) {
            int s0 = __shfl(idxv, j),     s1 = __shfl(idxv, j + 1);
            int s2 = __shfl(idxv, j + 2), s3 = __shfl(idxv, j + 3);
            float v0 = bf2f(z[(size_t)s0 * 128 + zoff + lane]);
            float v1 = bf2f(z[(size_t)s1 * 128 + zoff + lane]);
            float v2 = bf2f(z[(size_t)s2 * 128 + zoff + lane]);
            float v3 = bf2f(z[(size_t)s3 * 128 + zoff + lane]);
            acc += (v0 + v1) + (v2 + v3);
        }
        for (; j < cnt; ++j) {
            int s0 = __shfl(idxv, j);
            acc += bf2f(z[(size_t)s0 * 128 + zoff + lane]);
        }
    }
    return acc;
}

__global__ __launch_bounds__(256) void round2_k(const unsigned short* __restrict__ zc,
                                                const int* __restrict__ rs1,
                                                const int* __restrict__ csr1,
                                                const int* __restrict__ rs2,
                                                const int* __restrict__ csr2,
                                                float* __restrict__ logits) {
    int wave = threadIdx.x >> 6, lane = threadIdx.x & 63;
    int row = blockIdx.x * 4 + wave;

    float acc = gatherZ(zc, 0,  csr1, rs1[row], rs1[row + 1], lane)
              + gatherZ(zc, 64, csr2, rs2[row], rs2[row + 1], lane);

    float v = -1e30f;
    if (lane < 40) v = logits[(size_t)row * 40 + lane] + acc;
    float m = v;
    #pragma unroll
    for (int off = 32; off; off >>= 1) m = fmaxf(m, __shfl_xor(m, off));
    float ex = (lane < 40) ? __expf(v - m) : 0.f;
    float ssum = ex;
    #pragma unroll
    for (int off = 32; off; off >>= 1) ssum += __shfl_xor(ssum, off);
    float ls = __logf(ssum);
    if (lane < 40) logits[(size_t)row * 40 + lane] = v - m - ls;
}

// ---------------- launch ----------------

extern "C" void kernel_launch(void* const* d_in, const int* in_sizes, int n_in,
                              void* d_out, int out_size, void* d_ws, size_t ws_size,
                              hipStream_t stream) {
    const float* x       = (const float*)d_in[0];
    const float* W_embed = (const float*)d_in[1];
    const float* b_embed = (const float*)d_in[2];
    const float* W_cls   = (const float*)d_in[3];
    const float* b_cls   = (const float*)d_in[4];
    const int* a1src = (const int*)d_in[5];
    const int* a1dst = (const int*)d_in[6];
    const int* a2src = (const int*)d_in[7];
    const int* a2dst = (const int*)d_in[8];

    float* logits = (float*)d_out;
    float* ws = (float*)d_ws;

    // ws layout (units: 4B elements)
    const size_t OFF_HCAT = 0;          // N*192 bf16 = 9.6M floats
    const size_t OFF_ZCAT = 9600000;    // N*128 bf16 = 6.4M floats
    const size_t OFF_RS1  = 16000000;   // N+1 ints
    const size_t OFF_RS2  = 16100004;
    const size_t OFF_CUR1 = 16200008;   // N ints
    const size_t OFF_CUR2 = 16300008;
    const size_t OFF_BS1  = 16400008;   // 128 ints
    const size_t OFF_BS2  = 16400136;
    const size_t OFF_CSR1 = 16400264;   // E ints
    const size_t OFF_CSR2 = 18000264;
    const size_t OFF_WBF  = 19600264;   // 32768 ushorts
    const size_t OFF_WBIG = 19616648;   // 24576 ushorts

    unsigned short* hcat = (unsigned short*)(ws + OFF_HCAT);
    unsigned short* zcat = (unsigned short*)(ws + OFF_ZCAT);
    int* rs1  = (int*)(ws + OFF_RS1);
    int* rs2  = (int*)(ws + OFF_RS2);
    int* cur1 = (int*)(ws + OFF_CUR1);
    int* cur2 = (int*)(ws + OFF_CUR2);
    int* bs1  = (int*)(ws + OFF_BS1);
    int* bs2  = (int*)(ws + OFF_BS2);
    int* csr1 = (int*)(ws + OFF_CSR1);
    int* csr2 = (int*)(ws + OFF_CSR2);
    unsigned short* wbf  = (unsigned short*)(ws + OFF_WBF);
    unsigned short* wbig = (unsigned short*)(ws + OFF_WBIG);

    hipMemsetAsync(ws + OFF_RS1, 0, (OFF_CSR1 - OFF_RS1) * 4, stream);

    const int NB = 98;  // ceil((N+1)/1024)

    hist_k<<<EE / 256, 256, 0, stream>>>(a1dst, a2dst, rs1, rs2);
    scan_blocks_k<<<dim3(NB, 2), 256, 0, stream>>>(rs1, rs2, bs1, bs2, NN + 1);
    scan_totals_k<<<2, 128, 0, stream>>>(bs1, bs2, NB);
    scan_add_k<<<dim3(NB, 2), 256, 0, stream>>>(rs1, rs2, bs1, bs2, NN + 1);
    scatter_k<<<EE / 256, 256, 0, stream>>>(a1src, a1dst, a2src, a2dst,
                                            rs1, rs2, cur1, cur2, csr1, csr2);

    wconv_k<<<128, 256, 0, stream>>>(W_embed, wbf);
    wcls_k<<<96, 256, 0, stream>>>(W_cls, wbig);
    embed_k<<<(NN + 63) / 64, 256, 0, stream>>>(x, wbf, b_embed, hcat);

    round1_k<<<NN / 4, 256, 0, stream>>>(hcat, rs1, csr1, rs2, csr2);
    gemm_k<<<(NN + 63) / 64, 256, 0, stream>>>(hcat, wbig, b_cls, logits, zcat);
    round2_k<<<NN / 4, 256, 0, stream>>>(zcat, rs1, csr1, rs2, csr2, logits);
}

// Round 5
// 350.777 us; speedup vs baseline: 3.2262x; 1.6138x over previous
//
#include <hip/hip_runtime.h>
#include <hip/hip_bf16.h>

#define NN 100000
#define EE 1600000
#define NBK 196      // buckets = ceil(N / 512)
#define BSH 9        // bucket shift: 512 nodes per bucket
#define EPB 4096     // edges per block in binA/bhist
#define STG 10240    // binB LDS staging entries (mean 8192 + 22 sigma)

using frag8 = __attribute__((ext_vector_type(8))) short;
using f32x4 = __attribute__((ext_vector_type(4))) float;

__device__ inline unsigned short f2bf(float f) {
    unsigned u = __float_as_uint(f);
    u = u + 0x7FFFu + ((u >> 16) & 1u);   // RNE
    return (unsigned short)(u >> 16);
}
__device__ inline float bf2f(unsigned short u) {
    return __uint_as_float(((unsigned)u) << 16);
}

// ---------------- CSR build: bucketed, write-coalesced ----------------

__global__ __launch_bounds__(256) void bhist_k(const int* __restrict__ d1,
                                               const int* __restrict__ d2,
                                               int* __restrict__ bcnt) {
    __shared__ int lh[NBK];
    int adj = blockIdx.y;
    const int* dd = adj ? d2 : d1;
    int t = threadIdx.x;
    for (int i = t; i < NBK; i += 256) lh[i] = 0;
    __syncthreads();
    int e0 = blockIdx.x * EPB;
    #pragma unroll
    for (int k = 0; k < 16; ++k) {
        int e = e0 + k * 256 + t;
        if (e < EE) atomicAdd(&lh[dd[e] >> BSH], 1);
    }
    __syncthreads();
    for (int i = t; i < NBK; i += 256)
        if (lh[i]) atomicAdd(&bcnt[adj * NBK + i], lh[i]);
}

__global__ __launch_bounds__(256) void bscan_k(const int* __restrict__ bcnt,
                                               int* __restrict__ bbase,
                                               int* __restrict__ bcur) {
    int adj = blockIdx.x;
    __shared__ int s[256];
    int t = threadIdx.x;
    int v = (t < NBK) ? bcnt[adj * NBK + t] : 0;
    s[t] = v;
    __syncthreads();
    for (int off = 1; off < 256; off <<= 1) {
        int u = (t >= off) ? s[t - off] : 0;
        __syncthreads();
        s[t] += u;
        __syncthreads();
    }
    if (t < NBK) {
        int ex = s[t] - v;
        bbase[adj * (NBK + 1) + t] = ex;
        bcur[adj * NBK + t] = ex;
    }
    if (t == NBK - 1) bbase[adj * (NBK + 1) + NBK] = s[t];
}

__global__ __launch_bounds__(256) void binA_k(const int* __restrict__ s1,
                                              const int* __restrict__ d1,
                                              const int* __restrict__ s2,
                                              const int* __restrict__ d2,
                                              int* __restrict__ bcur,
                                              uint2* __restrict__ tmp1,
                                              uint2* __restrict__ tmp2) {
    __shared__ int lhist[NBK], lbase[NBK], gbase[NBK], lcur[NBK];
    __shared__ int sscan[256];
    __shared__ int stot;
    __shared__ uint2 stage[EPB];
    int adj = blockIdx.y;
    const int* ss = adj ? s2 : s1;
    const int* dd = adj ? d2 : d1;
    uint2* tmp = adj ? tmp2 : tmp1;
    int t = threadIdx.x;
    for (int i = t; i < NBK; i += 256) { lhist[i] = 0; lcur[i] = 0; }
    __syncthreads();
    int e0 = blockIdx.x * EPB;
    int d[16], s[16];
    #pragma unroll
    for (int k = 0; k < 16; ++k) {
        int e = e0 + k * 256 + t;
        d[k] = (e < EE) ? dd[e] : -1;
        s[k] = (e < EE) ? ss[e] : 0;
        if (d[k] >= 0) atomicAdd(&lhist[d[k] >> BSH], 1);
    }
    __syncthreads();
    // parallel exclusive scan of lhist -> lbase
    int hv = (t < NBK) ? lhist[t] : 0;
    sscan[t] = hv;
    __syncthreads();
    for (int off = 1; off < 256; off <<= 1) {
        int u = (t >= off) ? sscan[t - off] : 0;
        __syncthreads();
        sscan[t] += u;
        __syncthreads();
    }
    if (t < NBK) lbase[t] = sscan[t] - hv;
    if (t == NBK - 1) stot = sscan[t];
    __syncthreads();
    for (int i = t; i < NBK; i += 256)
        gbase[i] = lhist[i] ? atomicAdd(&bcur[adj * NBK + i], lhist[i]) : 0;
    __syncthreads();
    #pragma unroll
    for (int k = 0; k < 16; ++k) {
        if (d[k] >= 0) {
            int b = d[k] >> BSH;
            int pos = lbase[b] + atomicAdd(&lcur[b], 1);
            stage[pos] = make_uint2((unsigned)d[k], (unsigned)s[k]);
        }
    }
    __syncthreads();
    int tot = stot;
    for (int i = t; i < tot; i += 256) {
        uint2 u = stage[i];
        int b = u.x >> BSH;
        tmp[gbase[b] + (i - lbase[b])] = u;   // chunk-coalesced
    }
}

__global__ __launch_bounds__(256) void binB_k(const uint2* __restrict__ tmp1,
                                              const uint2* __restrict__ tmp2,
                                              const int* __restrict__ bbase,
                                              int* __restrict__ rs1,
                                              int* __restrict__ rs2,
                                              int* __restrict__ csr1,
                                              int* __restrict__ csr2) {
    __shared__ int cnt[512], cur[512];
    __shared__ int sscan[256];
    __shared__ int stage[STG];
    int adj = blockIdx.y, b = blockIdx.x;
    const uint2* tmp = adj ? tmp2 : tmp1;
    int* rs  = adj ? rs2  : rs1;
    int* csr = adj ? csr2 : csr1;
    int t = threadIdx.x;
    int n0 = b << BSH;
    int n1 = n0 + 512; if (n1 > NN) n1 = NN;
    int nn = n1 - n0;
    int base = bbase[adj * (NBK + 1) + b];
    int count = bbase[adj * (NBK + 1) + b + 1] - base;
    cnt[t] = 0; cnt[t + 256] = 0;
    __syncthreads();
    for (int i = t; i < count; i += 256)
        atomicAdd(&cnt[tmp[base + i].x - n0], 1);
    __syncthreads();
    // exclusive scan over 512 (2 entries/thread)
    int c0 = cnt[2 * t], c1 = cnt[2 * t + 1];
    int ps = c0 + c1;
    sscan[t] = ps;
    __syncthreads();
    for (int off = 1; off < 256; off <<= 1) {
        int u = (t >= off) ? sscan[t - off] : 0;
        __syncthreads();
        sscan[t] += u;
        __syncthreads();
    }
    int pe = sscan[t] - ps;
    int e0x = pe, e1x = pe + c0;
    if (2 * t < nn)     rs[n0 + 2 * t]     = base + e0x;
    if (2 * t + 1 < nn) rs[n0 + 2 * t + 1] = base + e1x;
    cur[2 * t] = e0x; cur[2 * t + 1] = e1x;
    if (t == 0 && n1 == NN) rs[NN] = base + count;
    __syncthreads();
    for (int i = t; i < count; i += 256) {
        uint2 u = tmp[base + i];
        int loc = atomicAdd(&cur[u.x - n0], 1);
        if (loc < STG) stage[loc] = (int)u.y;
        else csr[base + loc] = (int)u.y;   // statistical fallback, ~never
    }
    __syncthreads();
    int m = count < STG ? count : STG;
    for (int i = t; i < m; i += 256) csr[base + i] = stage[i];
}

// ---------------- W_embed fp32 -> bf16, transposed + chunk-swizzled (16-chunk groups) ----------------

__global__ void wconv_k(const float* __restrict__ W, unsigned short* __restrict__ Wbf) {
    int id = blockIdx.x * 256 + threadIdx.x;
    if (id < 512 * 64) {
        int k = id >> 6, col = id & 63;   // W row-major [512][64]
        int ch = k >> 3, el = k & 7;
        int cs = (ch & ~15) | ((ch & 15) ^ (col & 7));
        Wbf[col * 512 + cs * 8 + el] = f2bf(W[id]);
    }
}

// ---------------- W_cls -> Wbig bf16 [128 cols][192 k], 8-chunk-group swizzle ----------------

__global__ void wcls_k(const float* __restrict__ Wc, unsigned short* __restrict__ Wbig) {
    int id = blockIdx.x * 256 + threadIdx.x;   // 192*128
    int k = id >> 7, col = id & 127;
    float v = 0.f;
    if (col < 40) v = Wc[k * 40 + col];
    else if (col < 80)  { if (k >= 64) v = Wc[(192 + k - 64) * 40 + (col - 40)]; }
    else if (col < 120) { if (k >= 64) v = Wc[(320 + k - 64) * 40 + (col - 80)]; }
    int ch = k >> 3, el = k & 7;
    int phys = (ch & ~7) | ((ch & 7) ^ (col & 7));
    Wbig[col * 192 + phys * 8 + el] = f2bf(v);
}

// ---------------- embed: hcat[:,0:64] = relu(x @ W + b), bf16 MFMA ----------------

__global__ __launch_bounds__(256) void embed_k(const float* __restrict__ x,
                                               const unsigned short* __restrict__ Wbf,
                                               const float* __restrict__ bias,
                                               unsigned short* __restrict__ hcat) {
    __shared__ unsigned short sA[64 * 128];
    __shared__ unsigned short sW[64 * 128];
    int tid = threadIdx.x;
    int lane = tid & 63, wave = tid >> 6;
    int row0 = blockIdx.x * 64;
    f32x4 acc[4];
    #pragma unroll
    for (int n = 0; n < 4; n++) acc[n] = (f32x4){0.f, 0.f, 0.f, 0.f};

    int ccol = tid & 15;
    int rbase = tid >> 4;

    for (int kt = 0; kt < 4; ++kt) {
        #pragma unroll
        for (int rr = 0; rr < 4; ++rr) {
            int r = rbase + rr * 16;
            int grow = row0 + r;
            float v[8];
            if (grow < NN) {
                const float4* px = (const float4*)(x + (size_t)grow * 512 + kt * 128 + ccol * 8);
                float4 p0 = px[0], p1 = px[1];
                v[0] = p0.x; v[1] = p0.y; v[2] = p0.z; v[3] = p0.w;
                v[4] = p1.x; v[5] = p1.y; v[6] = p1.z; v[7] = p1.w;
            } else {
                #pragma unroll
                for (int i = 0; i < 8; i++) v[i] = 0.f;
            }
            unsigned uu[4];
            #pragma unroll
            for (int i = 0; i < 4; i++)
                uu[i] = (unsigned)f2bf(v[2 * i]) | ((unsigned)f2bf(v[2 * i + 1]) << 16);
            int cs = ccol ^ (r & 7);
            uint4 pk; pk.x = uu[0]; pk.y = uu[1]; pk.z = uu[2]; pk.w = uu[3];
            *(uint4*)&sA[(r * 16 + cs) * 8] = pk;
        }
        for (int q = tid; q < 1024; q += 256) {
            int col = q >> 4, c = q & 15;
            ((uint4*)sW)[q] = ((const uint4*)Wbf)[col * 64 + kt * 16 + c];
        }
        __syncthreads();
        #pragma unroll
        for (int kk = 0; kk < 4; ++kk) {
            int ar = wave * 16 + (lane & 15);
            int ac = (kk * 4 + (lane >> 4)) ^ (ar & 7);
            frag8 a = *(const frag8*)&sA[(ar * 16 + ac) * 8];
            #pragma unroll
            for (int n = 0; n < 4; n++) {
                int col = n * 16 + (lane & 15);
                int bc = (kk * 4 + (lane >> 4)) ^ (col & 7);
                frag8 b = *(const frag8*)&sW[(col * 16 + bc) * 8];
                acc[n] = __builtin_amdgcn_mfma_f32_16x16x32_bf16(a, b, acc[n], 0, 0, 0);
            }
        }
        __syncthreads();
    }
    #pragma unroll
    for (int n = 0; n < 4; n++) {
        int col = n * 16 + (lane & 15);
        float bv = bias[col];
        #pragma unroll
        for (int i = 0; i < 4; i++) {
            int r = row0 + wave * 16 + (lane >> 4) * 4 + i;
            if (r < NN) {
                float vv = acc[n][i] + bv;
                hcat[(size_t)r * 192 + col] = f2bf(vv > 0.f ? vv : 0.f);
            }
        }
    }
}

// ---------------- round 1: hcat[:,64:192] = [A1·h0 | A2·h0] ----------------

__device__ inline float gatherH0(const unsigned short* h, const int* __restrict__ csr,
                                 int s, int e, int lane) {
    float acc = 0.f;
    for (int t0 = s; t0 < e; t0 += 64) {
        int rem = e - t0;
        int idxv = 0;
        if (lane < rem) idxv = csr[t0 + lane];
        int cnt = rem < 64 ? rem : 64;
        int j = 0;
        for (; j + 4 <= cnt; j += 4) {
            int s0 = __shfl(idxv, j),     s1 = __shfl(idxv, j + 1);
            int s2 = __shfl(idxv, j + 2), s3 = __shfl(idxv, j + 3);
            float v0 = bf2f(h[(size_t)s0 * 192 + lane]);
            float v1 = bf2f(h[(size_t)s1 * 192 + lane]);
            float v2 = bf2f(h[(size_t)s2 * 192 + lane]);
            float v3 = bf2f(h[(size_t)s3 * 192 + lane]);
            acc += (v0 + v1) + (v2 + v3);
        }
        for (; j < cnt; ++j) {
            int s0 = __shfl(idxv, j);
            acc += bf2f(h[(size_t)s0 * 192 + lane]);
        }
    }
    return acc;
}

__global__ __launch_bounds__(256) void round1_k(unsigned short* hc,
                                                const int* __restrict__ rs1,
                                                const int* __restrict__ csr1,
                                                const int* __restrict__ rs2,
                                                const int* __restrict__ csr2) {
    int wave = threadIdx.x >> 6, lane = threadIdx.x & 63;
    int row = blockIdx.x * 4 + wave;

    float a1 = gatherH0(hc, csr1, rs1[row], rs1[row + 1], lane);
    float a2 = gatherH0(hc, csr2, rs2[row], rs2[row + 1], lane);

    hc[(size_t)row * 192 + 64 + lane]  = f2bf(a1);
    hc[(size_t)row * 192 + 128 + lane] = f2bf(a2);
}

// ---------------- gemm: [logits | z1 | z2] = hcat(Nx192) @ Wbig(192x120) ----------------

__global__ __launch_bounds__(256) void gemm_k(const unsigned short* __restrict__ hcat,
                                              const unsigned short* __restrict__ Wbig,
                                              const float* __restrict__ bc,
                                              float* __restrict__ logits,
                                              unsigned short* __restrict__ zcat) {
    __shared__ unsigned short sA[64 * 64];
    __shared__ unsigned short sB[128 * 64];
    int tid = threadIdx.x;
    int lane = tid & 63, wave = tid >> 6;
    int row0 = blockIdx.x * 64;
    f32x4 acc[8];
    #pragma unroll
    for (int n = 0; n < 8; n++) acc[n] = (f32x4){0.f, 0.f, 0.f, 0.f};

    for (int kt = 0; kt < 3; ++kt) {
        #pragma unroll
        for (int q = tid; q < 512; q += 256) {
            int r = q >> 3, c = q & 7;
            int phys = c ^ (r & 7);
            ((uint4*)sA)[r * 8 + phys] = ((const uint4*)hcat)[(size_t)(row0 + r) * 24 + kt * 8 + c];
        }
        #pragma unroll
        for (int q = tid; q < 1024; q += 256) {
            int col = q >> 3, c = q & 7;
            ((uint4*)sB)[q] = ((const uint4*)Wbig)[col * 24 + kt * 8 + c];
        }
        __syncthreads();
        #pragma unroll
        for (int kk = 0; kk < 2; ++kk) {
            int ar = wave * 16 + (lane & 15);
            int ac = (kk * 4 + (lane >> 4)) ^ (ar & 7);
            frag8 a = *(const frag8*)&sA[(ar * 8 + ac) * 8];
            #pragma unroll
            for (int n = 0; n < 8; n++) {
                int col = n * 16 + (lane & 15);
                int bcc = (kk * 4 + (lane >> 4)) ^ (col & 7);
                frag8 b = *(const frag8*)&sB[(col * 8 + bcc) * 8];
                acc[n] = __builtin_amdgcn_mfma_f32_16x16x32_bf16(a, b, acc[n], 0, 0, 0);
            }
        }
        __syncthreads();
    }
    #pragma unroll
    for (int n = 0; n < 8; n++) {
        int col = n * 16 + (lane & 15);
        float bv = (col < 40) ? bc[col] : 0.f;
        #pragma unroll
        for (int i = 0; i < 4; i++) {
            int r = row0 + wave * 16 + (lane >> 4) * 4 + i;
            if (r < NN) {
                float vv = acc[n][i];
                if (col < 40) {
                    logits[(size_t)r * 40 + col] = vv + bv;
                } else if (col < 80) {
                    zcat[(size_t)r * 128 + (col - 40)] = f2bf(vv);
                } else if (col < 120) {
                    zcat[(size_t)r * 128 + 64 + (col - 80)] = f2bf(vv);
                }
            }
        }
    }
}

// ---------------- round 2: logits += A1·z1 + A2·z2; log_softmax ----------------

__device__ inline float gatherZ(const unsigned short* __restrict__ z, int zoff,
                                const int* __restrict__ csr, int s, int e, int lane) {
    float acc = 0.f;
    for (int t0 = s; t0 < e; t0 += 64) {
        int rem = e - t0;
        int idxv = 0;
        if (lane < rem) idxv = csr[t0 + lane];
        int cnt = rem < 64 ? rem : 64;
        int j = 0;
        for (; j + 4 <= cnt; j += 4) {
            int s0 = __shfl(idxv, j),     s1 = __shfl(idxv, j + 1);
            int s2 = __shfl(idxv, j + 2), s3 = __shfl(idxv, j + 3);
            float v0 = bf2f(z[(size_t)s0 * 128 + zoff + lane]);
            float v1 = bf2f(z[(size_t)s1 * 128 + zoff + lane]);
            float v2 = bf2f(z[(size_t)s2 * 128 + zoff + lane]);
            float v3 = bf2f(z[(size_t)s3 * 128 + zoff + lane]);
            acc += (v0 + v1) + (v2 + v3);
        }
        for (; j < cnt; ++j) {
            int s0 = __shfl(idxv, j);
            acc += bf2f(z[(size_t)s0 * 128 + zoff + lane]);
        }
    }
    return acc;
}

__global__ __launch_bounds__(256) void round2_k(const unsigned short* __restrict__ zc,
                                                const int* __restrict__ rs1,
                                                const int* __restrict__ csr1,
                                                const int* __restrict__ rs2,
                                                const int* __restrict__ csr2,
                                                float* __restrict__ logits) {
    int wave = threadIdx.x >> 6, lane = threadIdx.x & 63;
    int row = blockIdx.x * 4 + wave;

    float acc = gatherZ(zc, 0,  csr1, rs1[row], rs1[row + 1], lane)
              + gatherZ(zc, 64, csr2, rs2[row], rs2[row + 1], lane);

    float v = -1e30f;
    if (lane < 40) v = logits[(size_t)row * 40 + lane] + acc;
    float m = v;
    #pragma unroll
    for (int off = 32; off; off >>= 1) m = fmaxf(m, __shfl_xor(m, off));
    float ex = (lane < 40) ? __expf(v - m) : 0.f;
    float ssum = ex;
    #pragma unroll
    for (int off = 32; off; off >>= 1) ssum += __shfl_xor(ssum, off);
    float ls = __logf(ssum);
    if (lane < 40) logits[(size_t)row * 40 + lane] = v - m - ls;
}

// ---------------- launch ----------------

extern "C" void kernel_launch(void* const* d_in, const int* in_sizes, int n_in,
                              void* d_out, int out_size, void* d_ws, size_t ws_size,
                              hipStream_t stream) {
    const float* x       = (const float*)d_in[0];
    const float* W_embed = (const float*)d_in[1];
    const float* b_embed = (const float*)d_in[2];
    const float* W_cls   = (const float*)d_in[3];
    const float* b_cls   = (const float*)d_in[4];
    const int* a1src = (const int*)d_in[5];
    const int* a1dst = (const int*)d_in[6];
    const int* a2src = (const int*)d_in[7];
    const int* a2dst = (const int*)d_in[8];

    float* logits = (float*)d_out;
    float* ws = (float*)d_ws;

    // ws layout (units: 4B elements)
    const size_t OFF_HCAT = 0;          // N*192 bf16 = 9.6M floats (also overlays tmp1/tmp2)
    const size_t OFF_ZCAT = 9600000;    // N*128 bf16 = 6.4M floats
    const size_t OFF_RS1  = 16000000;   // N+1 ints
    const size_t OFF_RS2  = 16100004;   // N+1 ints
    const size_t OFF_BB   = 16200008;   // bucketBase 2 x 197
    const size_t OFF_BC   = 16200402;   // bcur 2 x 196
    const size_t OFF_BCNT = 16200794;   // bucketCnt 2 x 196
    const size_t OFF_CSR1 = 16201188;   // E ints
    const size_t OFF_CSR2 = 17801188;   // E ints
    const size_t OFF_WBF  = 19401188;   // 32768 ushorts (16B aligned)
    const size_t OFF_WBIG = 19417572;   // 24576 ushorts

    unsigned short* hcat = (unsigned short*)(ws + OFF_HCAT);
    unsigned short* zcat = (unsigned short*)(ws + OFF_ZCAT);
    uint2* tmp1 = (uint2*)(ws + OFF_HCAT);        // overlay: used only before embed
    uint2* tmp2 = tmp1 + EE;
    int* rs1   = (int*)(ws + OFF_RS1);
    int* rs2   = (int*)(ws + OFF_RS2);
    int* bbase = (int*)(ws + OFF_BB);
    int* bcur  = (int*)(ws + OFF_BC);
    int* bcnt  = (int*)(ws + OFF_BCNT);
    int* csr1  = (int*)(ws + OFF_CSR1);
    int* csr2  = (int*)(ws + OFF_CSR2);
    unsigned short* wbf  = (unsigned short*)(ws + OFF_WBF);
    unsigned short* wbig = (unsigned short*)(ws + OFF_WBIG);

    hipMemsetAsync(ws + OFF_BCNT, 0, 392 * 4, stream);

    const int NBA = (EE + EPB - 1) / EPB;   // 391

    bhist_k<<<dim3(NBA, 2), 256, 0, stream>>>(a1dst, a2dst, bcnt);
    bscan_k<<<2, 256, 0, stream>>>(bcnt, bbase, bcur);
    binA_k<<<dim3(NBA, 2), 256, 0, stream>>>(a1src, a1dst, a2src, a2dst, bcur, tmp1, tmp2);
    binB_k<<<dim3(NBK, 2), 256, 0, stream>>>(tmp1, tmp2, bbase, rs1, rs2, csr1, csr2);

    wconv_k<<<128, 256, 0, stream>>>(W_embed, wbf);
    wcls_k<<<96, 256, 0, stream>>>(W_cls, wbig);
    embed_k<<<(NN + 63) / 64, 256, 0, stream>>>(x, wbf, b_embed, hcat);

    round1_k<<<NN / 4, 256, 0, stream>>>(hcat, rs1, csr1, rs2, csr2);
    gemm_k<<<(NN + 63) / 64, 256, 0, stream>>>(hcat, wbig, b_cls, logits, zcat);
    round2_k<<<NN / 4, 256, 0, stream>>>(zcat, rs1, csr1, rs2, csr2, logits);
}